// Round 8
// baseline (277.029 us; speedup 1.0000x reference)
//
#include <hip/hip_runtime.h>
#include <hip/hip_cooperative_groups.h>
#include <math.h>

namespace cg = cooperative_groups;

#define DDIM 128
#define NSEQ 8192
#define SUB 16        // steps per unit in seg phase
#define SEG 64        // steps per block (4 units)
#define NSEGB 128     // 8192/64 -> 128 segment matrices
#define NTRI 45       // lower-triangular entries (L,q), q<=L, L=0..8

#define TRI(L,q) ((L)*((L)+1)/2 + (q))

// ws layout (bytes)
#define OFF_MSEG 0                      // float2 [128][45][128] = 5898240
#define OFF_MT1  5898240                // float2 [32][45][128]  = 1474560
#define OFF_MT2  7372800                // float2 [8][45][128]   = 368640
// total ~7.7 MB

// ---------------------------------------------------------- reg helpers ----
__device__ __forceinline__ void loadG(const float2* __restrict__ p, int fq,
                                      float (&R)[NTRI], float (&I)[NTRI]) {
#pragma unroll
  for (int e = 0; e < NTRI; ++e) {
    float2 t = p[e*128 + fq];
    R[e] = t.x; I[e] = t.y;
  }
}

__device__ __forceinline__ void publish(float2* __restrict__ b, int fq,
                                        const float (&R)[NTRI], const float (&I)[NTRI]) {
#pragma unroll
  for (int e = 0; e < NTRI; ++e) b[e*128 + fq] = make_float2(R[e], I[e]);
}

// v <- G v  (9x9 lower-triangular complex, in-place descending L)
__device__ __forceinline__ void matvec(const float (&GR)[NTRI], const float (&GI)[NTRI],
                                       float (&vr)[9], float (&vi)[9]) {
#pragma unroll
  for (int L = 8; L >= 0; --L) {
    float sr = 0.f, si = 0.f;
#pragma unroll
    for (int q = 0; q <= L; ++q) {
      float xr = vr[q], xi = vi[q];
      sr += GR[TRI(L,q)]*xr - GI[TRI(L,q)]*xi;
      si += GR[TRI(L,q)]*xi + GI[TRI(L,q)]*xr;
    }
    vr[L] = sr; vi[L] = si;
  }
}

// Acc <- B * Acc with B streamed row-by-row from LDS (live regs ~135: no
// spill at the 128-VGPR allocation; LDS latency, not global)
__device__ __forceinline__ void matmulS(const float2* __restrict__ b, int fq,
                                        float (&Ar)[NTRI], float (&Ai)[NTRI]) {
#pragma unroll
  for (int L = 8; L >= 0; --L) {
    float Br_[9], Bi_[9];
#pragma unroll
    for (int r = 0; r <= L; ++r) {
      float2 t = b[TRI(L,r)*128 + fq];
      Br_[r] = t.x; Bi_[r] = t.y;
    }
    float tr[9], ti[9];
#pragma unroll
    for (int q = 0; q <= L; ++q) {
      float sr = 0.f, si = 0.f;
#pragma unroll
      for (int r = q; r <= L; ++r) {
        float ar = Ar[TRI(r,q)], ai = Ai[TRI(r,q)];
        sr += Br_[r]*ar - Bi_[r]*ai;
        si += Br_[r]*ai + Bi_[r]*ar;
      }
      tr[q] = sr; ti[q] = si;
    }
#pragma unroll
    for (int q = 0; q <= L; ++q) { Ar[TRI(L,q)] = tr[q]; Ai[TRI(L,q)] = ti[q]; }
  }
}

// ------------------------------------------------------------ mega-kernel --
// 128 blocks x 512 threads, cooperative. LDS ~137 KB -> 1 block/CU.
__global__ __launch_bounds__(512)
void sk_mega(const int* __restrict__ seq,
             const float* __restrict__ hw,    // [8][128][4]
             const float* __restrict__ sw,    // [8][4]
             float2* __restrict__ mseg,       // ws [128][45][128]
             float2* __restrict__ mt1,        // ws [32][45][128]
             float2* __restrict__ mt2,        // ws [8][45][128]
             float* __restrict__ out)
{
  __shared__ float2 phS[4096];          // 32 KB   [c][p][k]
  __shared__ float2 tb[2][NTRI*128];    // 92 KB   tree buffers (also probs/ct/st scratch)
  __shared__ float2 abS[SEG*8];         // 4 KB
  __shared__ int    chS[SEG];
  __shared__ float2 vS[9*128];          // 9 KB    (phase E)
  __shared__ float  Ur[128], Ui[128], ct2[128], st2[128];  // 2 KB (phase E)

  cg::grid_group grid = cg::this_grid();
  const int tid = threadIdx.x;
  const int u   = tid >> 7, fq = tid & 127;
  const int m   = blockIdx.x;
  const int wave = tid >> 6, lane = tid & 63;

  // ================= Phase A: per-block phat (softmax + DFT) in LDS =======
  {
    float* probs = (float*)tb;          // 32*128 floats = 16 KB inside tb
    float* ct = probs + 32*128;         // 128
    float* st = ct + 128;               // 128

    // softmax over d for each (p,c) row; 8 waves, 4 rows each
    for (int r = wave; r < 32; r += 8) {
      const int p = r >> 2, c = r & 3;
      float h0 = hw[p*512 + lane*4 + c];
      float h1 = hw[p*512 + (lane+64)*4 + c];
      float mx = fmaxf(h0, h1);
      #pragma unroll
      for (int off = 1; off < 64; off <<= 1) mx = fmaxf(mx, __shfl_xor(mx, off));
      float e0 = expf(h0 - mx), e1 = expf(h1 - mx);
      float s = e0 + e1;
      #pragma unroll
      for (int off = 1; off < 64; off <<= 1) s += __shfl_xor(s, off);
      float inv = 1.0f / s;
      probs[r*128 + lane]      = e0 * inv;
      probs[r*128 + lane + 64] = e1 * inv;
    }
    if (tid < 128) {
      float th = 6.28318530717958647692f * (float)tid / 128.0f;
      ct[tid] = cosf(th); st[tid] = sinf(th);
    }
    // ab coefficients: thread tid covers (local step ts = tid>>3, Lm1 = tid&7)
    {
      const int ts = tid >> 3, Lm1 = tid & 7, L = Lm1 + 1;
      const int i = m*SEG + ts;
      int c0 = seq[i];
      bool valid = (c0 >= 0) && (c0 < 4);
      int cc = min(max(c0, 0), 3);
      bool gate = valid && (L <= i + 1);
      float z  = (float)L / (float)(i + 1);
      float sg = 1.0f / (1.0f + expf(-sw[Lm1*4 + cc]));
      abS[tid] = make_float2(gate ? (1.0f - z) : 1.0f, gate ? (z * sg) : 0.0f);
    }
    if (tid < SEG) chS[tid] = seq[m*SEG + tid];
    __syncthreads();

    // forward DFT: 4096 outputs / 512 threads = 8 each
    for (int o = tid; o < 4096; o += 512) {
      const int r = o >> 7, k = o & 127;
      const int p = r >> 2, c = r & 3;
      float ar = 0.f, ai = 0.f;
      for (int j = 0; j < 128; ++j) {
        float pv = probs[r*128 + j];
        int w = (j * k) & 127;
        ar += pv * ct[w];
        ai -= pv * st[w];
      }
      phS[(c*8 + p)*128 + k] = make_float2(ar, ai);
    }
    __syncthreads();   // phS/abS/chS ready; probs/ct/st (in tb) now dead
  }

  // ================= Phase B: 64-step segment matrix, in-block tree =======
  {
    float Mr[NTRI], Mi[NTRI];
    #pragma unroll
    for (int e = 0; e < NTRI; ++e) { Mr[e] = 0.f; Mi[e] = 0.f; }
    #pragma unroll
    for (int L = 0; L <= 8; ++L) Mr[TRI(L,L)] = 1.0f;

    const int t0 = u * SUB;
    for (int t = 0; t < SUB; ++t) {
      const int ts = t0 + t;
      const int c  = chS[ts];
      #pragma unroll
      for (int L = 8; L >= 1; --L) {
        float2 abv = abS[ts*8 + (L-1)];
        float2 Pv  = phS[(c*8 + (L-1))*128 + fq];
        const float a = abv.x;
        const float bPr = abv.y * Pv.x, bPi = abv.y * Pv.y;
        #pragma unroll
        for (int q = 0; q < L; ++q) {
          float xr = Mr[TRI(L-1,q)], xi = Mi[TRI(L-1,q)];
          Mr[TRI(L,q)] = a*Mr[TRI(L,q)] + (bPr*xr - bPi*xi);
          Mi[TRI(L,q)] = a*Mi[TRI(L,q)] + (bPr*xi + bPi*xr);
        }
        Mr[TRI(L,L)] *= a;
        Mi[TRI(L,L)] *= a;
      }
    }

    // in-block tree fold: unit0 ends with M3*M2*M1*M0
    if (u == 1 || u == 3) publish(tb[u >> 1], fq, Mr, Mi);
    __syncthreads();
    if (u == 0 || u == 2) matmulS(tb[u >> 1], fq, Mr, Mi);
    __syncthreads();
    if (u == 2) publish(tb[1], fq, Mr, Mi);
    __syncthreads();
    if (u == 0) {
      matmulS(tb[1], fq, Mr, Mi);
      #pragma unroll
      for (int e = 0; e < NTRI; ++e)
        mseg[((size_t)m*NTRI + e)*128 + fq] = make_float2(Mr[e], Mi[e]);
    }
  }

  __threadfence();
  grid.sync();

  // ================= Phase C: blocks 0..31 fold mseg 4 -> mt1 =============
  if (m < 32) {
    float Ar[NTRI], Ai[NTRI];
    loadG(mseg + (size_t)(m*4 + u) * NTRI * 128, fq, Ar, Ai);
    if (u == 1 || u == 3) publish(tb[u >> 1], fq, Ar, Ai);
    __syncthreads();
    if (u == 0 || u == 2) matmulS(tb[u >> 1], fq, Ar, Ai);
    __syncthreads();
    if (u == 2) publish(tb[1], fq, Ar, Ai);
    __syncthreads();
    if (u == 0) {
      matmulS(tb[1], fq, Ar, Ai);
      #pragma unroll
      for (int e = 0; e < NTRI; ++e)
        mt1[((size_t)m*NTRI + e)*128 + fq] = make_float2(Ar[e], Ai[e]);
    }
  }

  __threadfence();
  grid.sync();

  // ================= Phase D: blocks 0..7 fold mt1 4 -> mt2 ===============
  if (m < 8) {
    float Ar[NTRI], Ai[NTRI];
    loadG(mt1 + (size_t)(m*4 + u) * NTRI * 128, fq, Ar, Ai);
    if (u == 1 || u == 3) publish(tb[u >> 1], fq, Ar, Ai);
    __syncthreads();
    if (u == 0 || u == 2) matmulS(tb[u >> 1], fq, Ar, Ai);
    __syncthreads();
    if (u == 2) publish(tb[1], fq, Ar, Ai);
    __syncthreads();
    if (u == 0) {
      matmulS(tb[1], fq, Ar, Ai);
      #pragma unroll
      for (int e = 0; e < NTRI; ++e)
        mt2[((size_t)m*NTRI + e)*128 + fq] = make_float2(Ar[e], Ai[e]);
    }
  }

  __threadfence();
  grid.sync();

  // ================= Phase E: block 0 folds mt2 (8) + matvec + iDFT =======
  if (m == 0) {
    float Ar[NTRI], Ai[NTRI];
    loadG(mt2 + (size_t)u * NTRI * 128, fq, Ar, Ai);   // M0..M3
    if (tid < 128) {
      float th = 6.28318530717958647692f * (float)tid / 128.0f;
      ct2[tid] = cosf(th); st2[tid] = sinf(th);
    }

    // tree fold low half: P_lo = M3*M2*M1*M0
    if (u == 1 || u == 3) publish(tb[u >> 1], fq, Ar, Ai);
    __syncthreads();
    if (u == 0 || u == 2) matmulS(tb[u >> 1], fq, Ar, Ai);
    __syncthreads();
    if (u == 2) publish(tb[1], fq, Ar, Ai);
    __syncthreads();
    if (u == 0) {
      matmulS(tb[1], fq, Ar, Ai);                       // P_lo in u0 regs
      #pragma unroll
      for (int L = 0; L <= 8; ++L)                      // publish P_lo * e0
        vS[L*128 + fq] = make_float2(Ar[TRI(L,0)], Ai[TRI(L,0)]);
    }
    __syncthreads();                                    // vS ready; tb reusable

    // tree fold high half: P_hi = M7*M6*M5*M4
    loadG(mt2 + (size_t)(4 + u) * NTRI * 128, fq, Ar, Ai);
    if (u == 1 || u == 3) publish(tb[u >> 1], fq, Ar, Ai);
    __syncthreads();
    if (u == 0 || u == 2) matmulS(tb[u >> 1], fq, Ar, Ai);
    __syncthreads();
    if (u == 2) publish(tb[1], fq, Ar, Ai);
    __syncthreads();
    if (u == 0) {
      matmulS(tb[1], fq, Ar, Ai);                       // P_hi in u0 regs
      float vr[9], vi[9];
      #pragma unroll
      for (int L = 0; L <= 8; ++L) { float2 t = vS[L*128 + fq]; vr[L] = t.x; vi[L] = t.y; }
      matvec(Ar, Ai, vr, vi);                           // v = P_hi * (P_lo e0)
      Ur[fq] = vr[8]; Ui[fq] = vi[8];
    }
    __syncthreads();

    if (tid < 128) {
      // out[j] = (1/128) sum_k Re(U_k e^{+2pi i jk/128})
      float acc = 0.f;
      for (int k = 0; k < 128; ++k) {
        int w = (tid * k) & 127;
        acc += Ur[k]*ct2[w] - Ui[k]*st2[w];
      }
      out[tid] = acc * (1.0f/128.0f);
    }
  }
}

// ---------------------------------------------------------------- launch ---
extern "C" void kernel_launch(void* const* d_in, const int* in_sizes, int n_in,
                              void* d_out, int out_size, void* d_ws, size_t ws_size,
                              hipStream_t stream)
{
  const int*   seq = (const int*)d_in[0];
  const float* hw  = (const float*)d_in[1];
  const float* sw  = (const float*)d_in[2];

  char* base = (char*)d_ws;
  float2* mseg = (float2*)(base + OFF_MSEG);
  float2* mt1  = (float2*)(base + OFF_MT1);
  float2* mt2  = (float2*)(base + OFF_MT2);
  float*  outp = (float*)d_out;

  void* params[] = { (void*)&seq, (void*)&hw, (void*)&sw,
                     (void*)&mseg, (void*)&mt1, (void*)&mt2, (void*)&outp };
  hipLaunchCooperativeKernel(reinterpret_cast<void*>(sk_mega),
                             dim3(NSEGB), dim3(512), params, 0, stream);
}

// Round 9
// 184.103 us; speedup vs baseline: 1.5048x; 1.5048x over previous
//
#include <hip/hip_runtime.h>
#include <math.h>

#define DDIM 128
#define NSEQ 8192
#define SUB 16        // steps per unit in sk_seg
#define SEG 64        // steps per seg block (4 units)
#define NSEGB 128     // 8192/64 -> 128 segment matrices
#define NTRI 45       // lower-triangular entries (L,q), q<=L, L=0..8

#define TRI(L,q) ((L)*((L)+1)/2 + (q))

// ws layout (bytes)
#define OFF_PHAT 0                      // float2 [4][8][128]    = 32768
#define OFF_MSEG 32768                  // float2 [128][45][128] = 5898240
#define OFF_MT1  5931008                // float2 [32][45][128]  = 1474560
// total ~7.4 MB

// ---------------------------------------------------------- reg helpers ----
__device__ __forceinline__ void loadG(const float2* __restrict__ p, int fq,
                                      float (&R)[NTRI], float (&I)[NTRI]) {
#pragma unroll
  for (int e = 0; e < NTRI; ++e) {
    float2 t = p[e*128 + fq];
    R[e] = t.x; I[e] = t.y;
  }
}

__device__ __forceinline__ void publish(float2* __restrict__ b, int fq,
                                        const float (&R)[NTRI], const float (&I)[NTRI]) {
#pragma unroll
  for (int e = 0; e < NTRI; ++e) b[e*128 + fq] = make_float2(R[e], I[e]);
}

// v <- G v  (9x9 lower-triangular complex, in-place descending L)
__device__ __forceinline__ void matvec(const float (&GR)[NTRI], const float (&GI)[NTRI],
                                       float (&vr)[9], float (&vi)[9]) {
#pragma unroll
  for (int L = 8; L >= 0; --L) {
    float sr = 0.f, si = 0.f;
#pragma unroll
    for (int q = 0; q <= L; ++q) {
      float xr = vr[q], xi = vi[q];
      sr += GR[TRI(L,q)]*xr - GI[TRI(L,q)]*xi;
      si += GR[TRI(L,q)]*xi + GI[TRI(L,q)]*xr;
    }
    vr[L] = sr; vi[L] = si;
  }
}

// Acc <- B * Acc with B streamed row-by-row from LDS (live regs ~135 -> no
// spill; LDS latency only, never global)
__device__ __forceinline__ void matmulS(const float2* __restrict__ b, int fq,
                                        float (&Ar)[NTRI], float (&Ai)[NTRI]) {
#pragma unroll
  for (int L = 8; L >= 0; --L) {
    float Br_[9], Bi_[9];
#pragma unroll
    for (int r = 0; r <= L; ++r) {
      float2 t = b[TRI(L,r)*128 + fq];
      Br_[r] = t.x; Bi_[r] = t.y;
    }
    float tr[9], ti[9];
#pragma unroll
    for (int q = 0; q <= L; ++q) {
      float sr = 0.f, si = 0.f;
#pragma unroll
      for (int r = q; r <= L; ++r) {
        float ar = Ar[TRI(r,q)], ai = Ai[TRI(r,q)];
        sr += Br_[r]*ar - Bi_[r]*ai;
        si += Br_[r]*ai + Bi_[r]*ar;
      }
      tr[q] = sr; ti[q] = si;
    }
#pragma unroll
    for (int q = 0; q <= L; ++q) { Ar[TRI(L,q)] = tr[q]; Ai[TRI(L,q)] = ti[q]; }
  }
}

// --------------------------------------------------------- phat setup -----
// 32 blocks x 128: one (p,c) row each -> softmax over d, forward DFT.
__global__ __launch_bounds__(128)
void sk_phat(const float* __restrict__ hw,    // [8][128][4]
             float2* __restrict__ phat)       // out [4][8][128]
{
  __shared__ float probs[128];
  __shared__ float ct[128], st[128];
  __shared__ float red[4];
  const int tid = threadIdx.x;
  const int r = blockIdx.x, p = r >> 2, c = r & 3;
  const int wave = tid >> 6, lane = tid & 63;

  float h = hw[p*512 + tid*4 + c];
  float mx = h;
  #pragma unroll
  for (int off = 1; off < 64; off <<= 1) mx = fmaxf(mx, __shfl_xor(mx, off));
  if (lane == 0) red[wave] = mx;
  __syncthreads();
  mx = fmaxf(red[0], red[1]);
  float e = expf(h - mx);
  float s = e;
  #pragma unroll
  for (int off = 1; off < 64; off <<= 1) s += __shfl_xor(s, off);
  if (lane == 0) red[2 + wave] = s;
  float th = 6.28318530717958647692f * (float)tid / 128.0f;
  ct[tid] = cosf(th); st[tid] = sinf(th);
  __syncthreads();
  s = red[2] + red[3];
  probs[tid] = e / s;
  __syncthreads();

  float ar = 0.f, ai = 0.f;
  for (int j = 0; j < 128; ++j) {
    float pv = probs[j];
    int w = (j * tid) & 127;
    ar += pv * ct[w];
    ai -= pv * st[w];
  }
  phat[(c*8 + p)*128 + tid] = make_float2(ar, ai);
}

// ------------------------------------------- 64-step segment matrices -----
// 128 blocks x 512 threads: unit u = tid>>7 builds a 16-step matrix in regs,
// then 2-level in-block tree (B streamed from LDS) -> one matrix per block.
// ab coefficients computed inline (exactly 1 (i,L) pair per thread).
__global__ __launch_bounds__(512)
void sk_seg(const int* __restrict__ seq,
            const float* __restrict__ sw,     // [8][4]
            const float2* __restrict__ phat_g,
            float2* __restrict__ mseg)
{
  __shared__ float2 phS[4096];          // 32 KB  [c][p][k]
  __shared__ float2 abS[SEG*8];         // 4 KB
  __shared__ int    chS[SEG];
  __shared__ float2 tb[2][NTRI*128];    // 92 KB tree buffers
  const int tid = threadIdx.x;
  const int u   = tid >> 7, fq = tid & 127;
  const int m   = blockIdx.x;

  {
    const float4* src = (const float4*)phat_g;
    float4* dst = (float4*)phS;
    for (int i = tid; i < 2048; i += 512) dst[i] = src[i];
  }
  if (tid < SEG) chS[tid] = seq[m*SEG + tid];
  {
    // thread tid covers (local step ts = tid>>3, level Lm1 = tid&7)
    const int ts = tid >> 3, Lm1 = tid & 7, L = Lm1 + 1;
    const int i = m*SEG + ts;
    int c0 = seq[i];
    bool valid = (c0 >= 0) && (c0 < 4);
    int cc = min(max(c0, 0), 3);
    bool gate = valid && (L <= i + 1);
    float z  = (float)L / (float)(i + 1);
    float sg = 1.0f / (1.0f + expf(-sw[Lm1*4 + cc]));
    abS[tid] = make_float2(gate ? (1.0f - z) : 1.0f, gate ? (z * sg) : 0.0f);
  }
  __syncthreads();

  float Mr[NTRI], Mi[NTRI];
  #pragma unroll
  for (int e = 0; e < NTRI; ++e) { Mr[e] = 0.f; Mi[e] = 0.f; }
  #pragma unroll
  for (int L = 0; L <= 8; ++L) Mr[TRI(L,L)] = 1.0f;

  const int t0 = u * SUB;
  for (int t = 0; t < SUB; ++t) {
    const int ts = t0 + t;
    const int c  = chS[ts];
    // row_L <- a*row_L + b*Phat[L-1]*row_{L-1}, in-place descending L
    #pragma unroll
    for (int L = 8; L >= 1; --L) {
      float2 abv = abS[ts*8 + (L-1)];
      float2 Pv  = phS[(c*8 + (L-1))*128 + fq];
      const float a = abv.x;
      const float bPr = abv.y * Pv.x, bPi = abv.y * Pv.y;
      #pragma unroll
      for (int q = 0; q < L; ++q) {
        float xr = Mr[TRI(L-1,q)], xi = Mi[TRI(L-1,q)];
        Mr[TRI(L,q)] = a*Mr[TRI(L,q)] + (bPr*xr - bPi*xi);
        Mi[TRI(L,q)] = a*Mi[TRI(L,q)] + (bPr*xi + bPi*xr);
      }
      Mr[TRI(L,L)] *= a;
      Mi[TRI(L,L)] *= a;
    }
  }

  // tree stage 1: units 1,3 publish; units 0,2 left-multiply from LDS
  if (u == 1 || u == 3) publish(tb[u >> 1], fq, Mr, Mi);
  __syncthreads();
  if (u == 0 || u == 2) matmulS(tb[u >> 1], fq, Mr, Mi);
  __syncthreads();
  // tree stage 2: unit 2 publishes P23; unit 0 forms P23*P01 and stores
  if (u == 2) publish(tb[1], fq, Mr, Mi);
  __syncthreads();
  if (u == 0) {
    matmulS(tb[1], fq, Mr, Mi);
    #pragma unroll
    for (int e = 0; e < NTRI; ++e)
      mseg[((size_t)m*NTRI + e)*128 + fq] = make_float2(Mr[e], Mi[e]);
  }
}

// ------------------------------------------- pairwise tree: fold 4 -> 1 ---
// Block g folds in[4g..4g+3] -> out[g]. Each unit loads ONE matrix (all
// global loads parallel), then 2-level in-block LDS tree. (round-6 proven)
__global__ __launch_bounds__(512)
void sk_comb(const float2* __restrict__ min_, float2* __restrict__ mout)
{
  __shared__ float2 tb[2][NTRI*128];    // 92 KB
  const int tid = threadIdx.x;
  const int u   = tid >> 7, fq = tid & 127;
  const int g   = blockIdx.x;

  float Ar[NTRI], Ai[NTRI];
  loadG(min_ + (size_t)(g*4 + u) * NTRI * 128, fq, Ar, Ai);

  if (u == 1 || u == 3) publish(tb[u >> 1], fq, Ar, Ai);
  __syncthreads();
  if (u == 0 || u == 2) matmulS(tb[u >> 1], fq, Ar, Ai);
  __syncthreads();
  if (u == 2) publish(tb[1], fq, Ar, Ai);
  __syncthreads();
  if (u == 0) {
    matmulS(tb[1], fq, Ar, Ai);
    #pragma unroll
    for (int e = 0; e < NTRI; ++e)
      mout[((size_t)g*NTRI + e)*128 + fq] = make_float2(Ar[e], Ai[e]);
  }
}

// -------------- final: fold 32 matrices in 8 tree-groups + iDFT -----------
// 1 block x 512 threads. Per group of 4: each unit loads ONE matrix in
// parallel (no serial global streaming), 2-level LDS tree -> P_g in unit 0,
// then unit 0 applies v <- P_g v (v = running e0-image, in registers).
// U_k = v[8]; iDFT; write.
__global__ __launch_bounds__(512, 2)
void sk_fin32(const float2* __restrict__ mg, float* __restrict__ out)
{
  __shared__ float2 tb[2][NTRI*128];    // 92 KB tree buffers
  __shared__ float Ur[128], Ui[128], ct[128], st[128];
  const int tid = threadIdx.x;
  const int u   = tid >> 7, fq = tid & 127;

  if (tid < 128) {
    float th = 6.28318530717958647692f * (float)tid / 128.0f;
    ct[tid] = cosf(th); st[tid] = sinf(th);
  }

  float vr[9], vi[9];
  #pragma unroll
  for (int L = 0; L <= 8; ++L) { vr[L] = 0.f; vi[L] = 0.f; }
  vr[0] = 1.0f;   // e0

  for (int g = 0; g < 8; ++g) {
    float Ar[NTRI], Ai[NTRI];
    loadG(mg + (size_t)(g*4 + u) * NTRI * 128, fq, Ar, Ai);
    if (u == 1 || u == 3) publish(tb[u >> 1], fq, Ar, Ai);
    __syncthreads();
    if (u == 0 || u == 2) matmulS(tb[u >> 1], fq, Ar, Ai);
    __syncthreads();
    if (u == 2) publish(tb[1], fq, Ar, Ai);
    __syncthreads();
    if (u == 0) {
      matmulS(tb[1], fq, Ar, Ai);        // P_g = M_{4g+3}..M_{4g}
      matvec(Ar, Ai, vr, vi);            // v <- P_g v
    }
    __syncthreads();                      // tb free for next group
  }

  if (u == 0) { Ur[fq] = vr[8]; Ui[fq] = vi[8]; }
  __syncthreads();

  if (tid < 128) {
    // out[j] = (1/128) sum_k Re(U_k e^{+2pi i jk/128})
    float acc = 0.f;
    for (int k = 0; k < 128; ++k) {
      int w = (tid * k) & 127;
      acc += Ur[k]*ct[w] - Ui[k]*st[w];
    }
    out[tid] = acc * (1.0f/128.0f);
  }
}

// ---------------------------------------------------------------- launch ---
extern "C" void kernel_launch(void* const* d_in, const int* in_sizes, int n_in,
                              void* d_out, int out_size, void* d_ws, size_t ws_size,
                              hipStream_t stream)
{
  const int*   seq = (const int*)d_in[0];
  const float* hw  = (const float*)d_in[1];
  const float* sw  = (const float*)d_in[2];

  char* base = (char*)d_ws;
  float2* phat = (float2*)(base + OFF_PHAT);
  float2* mseg = (float2*)(base + OFF_MSEG);
  float2* mt1  = (float2*)(base + OFF_MT1);

  sk_phat<<<32, 128, 0, stream>>>(hw, phat);
  sk_seg<<<NSEGB, 512, 0, stream>>>(seq, sw, phat, mseg);
  sk_comb<<<32, 512, 0, stream>>>(mseg, mt1);      // 128 -> 32
  sk_fin32<<<1, 512, 0, stream>>>(mt1, (float*)d_out);
}

// Round 10
// 126.110 us; speedup vs baseline: 2.1967x; 1.4599x over previous
//
#include <hip/hip_runtime.h>
#include <math.h>

#define DDIM 128
#define NSEQ 8192
#define SUB 16        // steps per unit in sk_seg
#define SEG 64        // steps per seg block (4 units)
#define NSEGB 128     // 8192/64 -> 128 segment matrices
#define NTRI 45       // lower-triangular entries (L,q), q<=L, L=0..8

#define TRI(L,q) ((L)*((L)+1)/2 + (q))

// ws layout (bytes)
#define OFF_PHAT 0                      // float2 [4][8][128]    = 32768
#define OFF_MSEG 32768                  // float2 [128][45][128] = 5898240
#define OFF_MT1  5931008                // float2 [32][45][128]  = 1474560
#define OFF_MT2  7405568                // float2 [8][45][128]   = 368640
// total ~7.8 MB

// ---------------------------------------------------------- reg helpers ----
__device__ __forceinline__ void loadG(const float2* __restrict__ p, int fq,
                                      float (&R)[NTRI], float (&I)[NTRI]) {
#pragma unroll
  for (int e = 0; e < NTRI; ++e) {
    float2 t = p[e*128 + fq];
    R[e] = t.x; I[e] = t.y;
  }
}

__device__ __forceinline__ void publish(float2* __restrict__ b, int fq,
                                        const float (&R)[NTRI], const float (&I)[NTRI]) {
#pragma unroll
  for (int e = 0; e < NTRI; ++e) b[e*128 + fq] = make_float2(R[e], I[e]);
}

// v <- G v  (9x9 lower-triangular complex, in-place descending L)
__device__ __forceinline__ void matvec(const float (&GR)[NTRI], const float (&GI)[NTRI],
                                       float (&vr)[9], float (&vi)[9]) {
#pragma unroll
  for (int L = 8; L >= 0; --L) {
    float sr = 0.f, si = 0.f;
#pragma unroll
    for (int q = 0; q <= L; ++q) {
      float xr = vr[q], xi = vi[q];
      sr += GR[TRI(L,q)]*xr - GI[TRI(L,q)]*xi;
      si += GR[TRI(L,q)]*xi + GI[TRI(L,q)]*xr;
    }
    vr[L] = sr; vi[L] = si;
  }
}

// Acc <- B * Acc with B streamed row-by-row from LDS (live regs ~135 -> no
// spill; never keep extra state live across this call!)
__device__ __forceinline__ void matmulS(const float2* __restrict__ b, int fq,
                                        float (&Ar)[NTRI], float (&Ai)[NTRI]) {
#pragma unroll
  for (int L = 8; L >= 0; --L) {
    float Br_[9], Bi_[9];
#pragma unroll
    for (int r = 0; r <= L; ++r) {
      float2 t = b[TRI(L,r)*128 + fq];
      Br_[r] = t.x; Bi_[r] = t.y;
    }
    float tr[9], ti[9];
#pragma unroll
    for (int q = 0; q <= L; ++q) {
      float sr = 0.f, si = 0.f;
#pragma unroll
      for (int r = q; r <= L; ++r) {
        float ar = Ar[TRI(r,q)], ai = Ai[TRI(r,q)];
        sr += Br_[r]*ar - Bi_[r]*ai;
        si += Br_[r]*ai + Bi_[r]*ar;
      }
      tr[q] = sr; ti[q] = si;
    }
#pragma unroll
    for (int q = 0; q <= L; ++q) { Ar[TRI(L,q)] = tr[q]; Ai[TRI(L,q)] = ti[q]; }
  }
}

// --------------------------------------------------------- phat setup -----
// 32 blocks x 128: one (p,c) row each -> softmax over d, forward DFT.
__global__ __launch_bounds__(128)
void sk_phat(const float* __restrict__ hw,    // [8][128][4]
             float2* __restrict__ phat)       // out [4][8][128]
{
  __shared__ float probs[128];
  __shared__ float ct[128], st[128];
  __shared__ float red[4];
  const int tid = threadIdx.x;
  const int r = blockIdx.x, p = r >> 2, c = r & 3;
  const int wave = tid >> 6, lane = tid & 63;

  float h = hw[p*512 + tid*4 + c];
  float mx = h;
  #pragma unroll
  for (int off = 1; off < 64; off <<= 1) mx = fmaxf(mx, __shfl_xor(mx, off));
  if (lane == 0) red[wave] = mx;
  __syncthreads();
  mx = fmaxf(red[0], red[1]);
  float e = expf(h - mx);
  float s = e;
  #pragma unroll
  for (int off = 1; off < 64; off <<= 1) s += __shfl_xor(s, off);
  if (lane == 0) red[2 + wave] = s;
  float th = 6.28318530717958647692f * (float)tid / 128.0f;
  ct[tid] = cosf(th); st[tid] = sinf(th);
  __syncthreads();
  s = red[2] + red[3];
  probs[tid] = e / s;
  __syncthreads();

  float ar = 0.f, ai = 0.f;
  for (int j = 0; j < 128; ++j) {
    float pv = probs[j];
    int w = (j * tid) & 127;
    ar += pv * ct[w];
    ai -= pv * st[w];
  }
  phat[(c*8 + p)*128 + tid] = make_float2(ar, ai);
}

// ------------------------------------------- 64-step segment matrices -----
// 128 blocks x 512 threads: unit u = tid>>7 builds a 16-step matrix in regs,
// then 2-level in-block tree (B streamed from LDS) -> one matrix per block.
// ab coefficients computed inline (exactly 1 (i,L) pair per thread).
__global__ __launch_bounds__(512)
void sk_seg(const int* __restrict__ seq,
            const float* __restrict__ sw,     // [8][4]
            const float2* __restrict__ phat_g,
            float2* __restrict__ mseg)
{
  __shared__ float2 phS[4096];          // 32 KB  [c][p][k]
  __shared__ float2 abS[SEG*8];         // 4 KB
  __shared__ int    chS[SEG];
  __shared__ float2 tb[2][NTRI*128];    // 92 KB tree buffers
  const int tid = threadIdx.x;
  const int u   = tid >> 7, fq = tid & 127;
  const int m   = blockIdx.x;

  {
    const float4* src = (const float4*)phat_g;
    float4* dst = (float4*)phS;
    for (int i = tid; i < 2048; i += 512) dst[i] = src[i];
  }
  if (tid < SEG) chS[tid] = seq[m*SEG + tid];
  {
    // thread tid covers (local step ts = tid>>3, level Lm1 = tid&7)
    const int ts = tid >> 3, Lm1 = tid & 7, L = Lm1 + 1;
    const int i = m*SEG + ts;
    int c0 = seq[i];
    bool valid = (c0 >= 0) && (c0 < 4);
    int cc = min(max(c0, 0), 3);
    bool gate = valid && (L <= i + 1);
    float z  = (float)L / (float)(i + 1);
    float sg = 1.0f / (1.0f + expf(-sw[Lm1*4 + cc]));
    abS[tid] = make_float2(gate ? (1.0f - z) : 1.0f, gate ? (z * sg) : 0.0f);
  }
  __syncthreads();

  float Mr[NTRI], Mi[NTRI];
  #pragma unroll
  for (int e = 0; e < NTRI; ++e) { Mr[e] = 0.f; Mi[e] = 0.f; }
  #pragma unroll
  for (int L = 0; L <= 8; ++L) Mr[TRI(L,L)] = 1.0f;

  const int t0 = u * SUB;
  for (int t = 0; t < SUB; ++t) {
    const int ts = t0 + t;
    const int c  = chS[ts];
    // row_L <- a*row_L + b*Phat[L-1]*row_{L-1}, in-place descending L
    #pragma unroll
    for (int L = 8; L >= 1; --L) {
      float2 abv = abS[ts*8 + (L-1)];
      float2 Pv  = phS[(c*8 + (L-1))*128 + fq];
      const float a = abv.x;
      const float bPr = abv.y * Pv.x, bPi = abv.y * Pv.y;
      #pragma unroll
      for (int q = 0; q < L; ++q) {
        float xr = Mr[TRI(L-1,q)], xi = Mi[TRI(L-1,q)];
        Mr[TRI(L,q)] = a*Mr[TRI(L,q)] + (bPr*xr - bPi*xi);
        Mi[TRI(L,q)] = a*Mi[TRI(L,q)] + (bPr*xi + bPi*xr);
      }
      Mr[TRI(L,L)] *= a;
      Mi[TRI(L,L)] *= a;
    }
  }

  // tree stage 1: units 1,3 publish; units 0,2 left-multiply from LDS
  if (u == 1 || u == 3) publish(tb[u >> 1], fq, Mr, Mi);
  __syncthreads();
  if (u == 0 || u == 2) matmulS(tb[u >> 1], fq, Mr, Mi);
  __syncthreads();
  // tree stage 2: unit 2 publishes P23; unit 0 forms P23*P01 and stores
  if (u == 2) publish(tb[1], fq, Mr, Mi);
  __syncthreads();
  if (u == 0) {
    matmulS(tb[1], fq, Mr, Mi);
    #pragma unroll
    for (int e = 0; e < NTRI; ++e)
      mseg[((size_t)m*NTRI + e)*128 + fq] = make_float2(Mr[e], Mi[e]);
  }
}

// ------------------------------------------- pairwise tree: fold 4 -> 1 ---
// Block g folds in[4g..4g+3] -> out[g]. Each unit loads ONE matrix (all
// global loads parallel), then 2-level in-block LDS tree. (round-6 proven)
__global__ __launch_bounds__(512)
void sk_comb(const float2* __restrict__ min_, float2* __restrict__ mout)
{
  __shared__ float2 tb[2][NTRI*128];    // 92 KB
  const int tid = threadIdx.x;
  const int u   = tid >> 7, fq = tid & 127;
  const int g   = blockIdx.x;

  float Ar[NTRI], Ai[NTRI];
  loadG(min_ + (size_t)(g*4 + u) * NTRI * 128, fq, Ar, Ai);

  if (u == 1 || u == 3) publish(tb[u >> 1], fq, Ar, Ai);
  __syncthreads();
  if (u == 0 || u == 2) matmulS(tb[u >> 1], fq, Ar, Ai);
  __syncthreads();
  if (u == 2) publish(tb[1], fq, Ar, Ai);
  __syncthreads();
  if (u == 0) {
    matmulS(tb[1], fq, Ar, Ai);
    #pragma unroll
    for (int e = 0; e < NTRI; ++e)
      mout[((size_t)g*NTRI + e)*128 + fq] = make_float2(Ar[e], Ai[e]);
  }
}

// ---------------- final: fold 8 matrices (two tree passes) + iDFT ---------
// 1 block x 512 threads (4 units; round-6 proven, no spills). Only the
// e0-image crosses between halves, via LDS col-0 publish:
// v = P_hi * (P_lo * e0); U_k = v[8]; iDFT; write.
__global__ __launch_bounds__(512)
void sk_fin8(const float2* __restrict__ mg, float* __restrict__ out)
{
  __shared__ float2 tb[2][NTRI*128];    // 92 KB tree buffers (reused)
  __shared__ float2 vS[9*128];          // P_lo * e0
  __shared__ float Ur[128], Ui[128], ct[128], st[128];
  const int tid = threadIdx.x;
  const int u   = tid >> 7, fq = tid & 127;

  float Ar[NTRI], Ai[NTRI];
  loadG(mg + (size_t)u * NTRI * 128, fq, Ar, Ai);   // M0..M3

  if (tid < 128) {
    float th = 6.28318530717958647692f * (float)tid / 128.0f;
    ct[tid] = cosf(th); st[tid] = sinf(th);
  }

  // ---- tree fold low half: P_lo = M3*M2*M1*M0 ----
  if (u == 1 || u == 3) publish(tb[u >> 1], fq, Ar, Ai);
  __syncthreads();
  if (u == 0 || u == 2) matmulS(tb[u >> 1], fq, Ar, Ai);
  __syncthreads();
  if (u == 2) publish(tb[1], fq, Ar, Ai);
  __syncthreads();
  if (u == 0) {
    matmulS(tb[1], fq, Ar, Ai);                     // P_lo in u0 regs
    #pragma unroll
    for (int L = 0; L <= 8; ++L)                    // publish P_lo * e0 (col 0)
      vS[L*128 + fq] = make_float2(Ar[TRI(L,0)], Ai[TRI(L,0)]);
  }
  __syncthreads();                                  // vS ready; tb reusable

  // ---- tree fold high half: P_hi = M7*M6*M5*M4 ----
  loadG(mg + (size_t)(4 + u) * NTRI * 128, fq, Ar, Ai);
  if (u == 1 || u == 3) publish(tb[u >> 1], fq, Ar, Ai);
  __syncthreads();
  if (u == 0 || u == 2) matmulS(tb[u >> 1], fq, Ar, Ai);
  __syncthreads();
  if (u == 2) publish(tb[1], fq, Ar, Ai);
  __syncthreads();
  if (u == 0) {
    matmulS(tb[1], fq, Ar, Ai);                     // P_hi in u0 regs
    float vr[9], vi[9];
    #pragma unroll
    for (int L = 0; L <= 8; ++L) { float2 t = vS[L*128 + fq]; vr[L] = t.x; vi[L] = t.y; }
    matvec(Ar, Ai, vr, vi);                         // v = P_hi * (P_lo e0)
    Ur[fq] = vr[8]; Ui[fq] = vi[8];
  }
  __syncthreads();

  if (tid < 128) {
    // out[j] = (1/128) sum_k Re(U_k e^{+2pi i jk/128})
    float acc = 0.f;
    for (int k = 0; k < 128; ++k) {
      int w = (tid * k) & 127;
      acc += Ur[k]*ct[w] - Ui[k]*st[w];
    }
    out[tid] = acc * (1.0f/128.0f);
  }
}

// ---------------------------------------------------------------- launch ---
extern "C" void kernel_launch(void* const* d_in, const int* in_sizes, int n_in,
                              void* d_out, int out_size, void* d_ws, size_t ws_size,
                              hipStream_t stream)
{
  const int*   seq = (const int*)d_in[0];
  const float* hw  = (const float*)d_in[1];
  const float* sw  = (const float*)d_in[2];

  char* base = (char*)d_ws;
  float2* phat = (float2*)(base + OFF_PHAT);
  float2* mseg = (float2*)(base + OFF_MSEG);
  float2* mt1  = (float2*)(base + OFF_MT1);
  float2* mt2  = (float2*)(base + OFF_MT2);

  sk_phat<<<32, 128, 0, stream>>>(hw, phat);
  sk_seg<<<NSEGB, 512, 0, stream>>>(seq, sw, phat, mseg);
  sk_comb<<<32, 512, 0, stream>>>(mseg, mt1);      // 128 -> 32
  sk_comb<<<8, 512, 0, stream>>>(mt1, mt2);        //  32 -> 8
  sk_fin8<<<1, 512, 0, stream>>>(mt2, (float*)d_out);
}